// Round 4
// baseline (15.989 us; speedup 1.0000x reference)
//
#include <hip/hip_runtime.h>
#include <math.h>

// out[b,q] = T_q(xmean_b) * inner_sum[b,q]/IN
//   inner_sum[b,q] = sum_p c[q]*sin(pi*(q+1)*x[b,p])*W[q,p]
//   xmean_b = (1/D) sum_q tanh(inner_sum[b,q]);  T_q(x)=cos(q*acos(x)), |xmean|<1
// theta input dead (corr == 0). sin in REVOLUTIONS: sin(pi*k*x) = v_sin((k/2)*x).
// LDS layout transposed: cw4[p4][q] = cq[q]*W[q][4p4..4p4+3] -> lane-contiguous b128 reads.

#define IN_DIM 100
#define MAXD   100
#define NP4    (IN_DIM / 4)     // 25
#define WAVES  8
#define BLK    (WAVES * 64)     // 512 threads
#define RPW    2                // batch rows per wave
#define ROWS   (WAVES * RPW)    // 16 rows per block -> grid 256 = 1 block/CU
#define INV2PI 0.15915494309189535f

__device__ __forceinline__ float fast_tanh(float v) {
    float e = __expf(2.0f * v);
    return 1.0f - 2.0f / (e + 1.0f);
}

__global__ __launch_bounds__(BLK) void kat_kernel(
    const float* __restrict__ x, const float* __restrict__ W,
    const int* __restrict__ dimp, float* __restrict__ out, int B)
{
    const int D = *dimp;
    const int P = (IN_DIM < D) ? IN_DIM : D;

    __shared__ float4 cw4[NP4][MAXD];   // 40 KB; [p4][q] so lane-indexed-by-q b128 is contiguous

    const int t = threadIdx.x;

    // stage cw4 (cq folded in; rows q>=D and cols p>=P zeroed -> main loop is D-independent)
    for (int idx = t; idx < NP4 * MAXD; idx += BLK) {
        int p4 = idx / MAXD;
        int q  = idx - p4 * MAXD;
        float k = (float)(q + 1);
        float c;
        if (q < 15) {
            c = 1.0f / k;
        } else {
            float qf = (float)q;
            float S = 1.0f + 0.2f * __logf(qf / 15.0f) * (1.0f - __expf(-0.03f * (qf - 15.0f)));
            c = 1.0f / (k * S);
        }
        c = (q < D) ? c * __expf(-0.03f * k * k) : 0.0f;
        float4 wv = ((const float4*)W)[q * (MAXD / 4) + p4];
        int p = 4 * p4;
        float4 v;
        v.x = (p     < P) ? c * wv.x : 0.0f;
        v.y = (p + 1 < P) ? c * wv.y : 0.0f;
        v.z = (p + 2 < P) ? c * wv.z : 0.0f;
        v.w = (p + 3 < P) ? c * wv.w : 0.0f;
        cw4[p4][q] = v;                 // contiguous by thread -> conflict-free write
    }
    __syncthreads();

    const int w    = t >> 6;
    const int lane = t & 63;
    const int row0 = blockIdx.x * ROWS;
    const int bA   = row0 + w * RPW;    // this wave's two batch rows
    const int bB   = bA + 1;

    // scalarize row base -> x loads become s_load_dwordx4 (SMEM broadcast, no LDS/VMEM)
    int buA = __builtin_amdgcn_readfirstlane((bA < B) ? bA : (B - 1));
    int buB = __builtin_amdgcn_readfirstlane((bB < B) ? bB : (B - 1));
    const float4* __restrict__ xA4 = (const float4*)(x + (size_t)buA * IN_DIM);
    const float4* __restrict__ xB4 = (const float4*)(x + (size_t)buB * IN_DIM);

    const int q0  = lane;
    const int q1  = lane + 64;
    const int q1c = (q1 < MAXD - 1) ? q1 : (MAXD - 1);   // clamp; garbage masked below
    const float m1 = (q1 < D) ? 1.0f : 0.0f;

    const float f0 = 0.5f * (float)(q0 + 1);  // revolutions: sin(pi*k*x) = sin2pi((k/2)x)
    const float f1 = 0.5f * (float)(q1 + 1);

    float a0A = 0.0f, a1A = 0.0f, a0B = 0.0f, a1B = 0.0f;
    #pragma unroll 5
    for (int p4 = 0; p4 < NP4; ++p4) {
        float4 xa = xA4[p4];            // wave-uniform scalar load
        float4 xb = xB4[p4];
        float4 c0 = cw4[p4][q0];        // lane-contiguous ds_read_b128
        float4 c1 = cw4[p4][q1c];       // lanes 36..63 broadcast row 99 (free)

        a0A = fmaf(__builtin_amdgcn_sinf(f0 * xa.x), c0.x, a0A);
        a1A = fmaf(__builtin_amdgcn_sinf(f1 * xa.x), c1.x, a1A);
        a0B = fmaf(__builtin_amdgcn_sinf(f0 * xb.x), c0.x, a0B);
        a1B = fmaf(__builtin_amdgcn_sinf(f1 * xb.x), c1.x, a1B);

        a0A = fmaf(__builtin_amdgcn_sinf(f0 * xa.y), c0.y, a0A);
        a1A = fmaf(__builtin_amdgcn_sinf(f1 * xa.y), c1.y, a1A);
        a0B = fmaf(__builtin_amdgcn_sinf(f0 * xb.y), c0.y, a0B);
        a1B = fmaf(__builtin_amdgcn_sinf(f1 * xb.y), c1.y, a1B);

        a0A = fmaf(__builtin_amdgcn_sinf(f0 * xa.z), c0.z, a0A);
        a1A = fmaf(__builtin_amdgcn_sinf(f1 * xa.z), c1.z, a1A);
        a0B = fmaf(__builtin_amdgcn_sinf(f0 * xb.z), c0.z, a0B);
        a1B = fmaf(__builtin_amdgcn_sinf(f1 * xb.z), c1.z, a1B);

        a0A = fmaf(__builtin_amdgcn_sinf(f0 * xa.w), c0.w, a0A);
        a1A = fmaf(__builtin_amdgcn_sinf(f1 * xa.w), c1.w, a1A);
        a0B = fmaf(__builtin_amdgcn_sinf(f0 * xb.w), c0.w, a0B);
        a1B = fmaf(__builtin_amdgcn_sinf(f1 * xb.w), c1.w, a1B);
    }
    a1A *= m1;                          // kill clamped-row garbage (q1 >= D)
    a1B *= m1;

    // q>=D rows staged as zero -> tanh(0)=0 contributes nothing
    float sA = fast_tanh(a0A) + fast_tanh(a1A);
    float sB = fast_tanh(a0B) + fast_tanh(a1B);
    #pragma unroll
    for (int m = 32; m; m >>= 1) {
        sA += __shfl_xor(sA, m);
        sB += __shfl_xor(sB, m);
    }
    const float thA = acosf(sA / (float)D) * INV2PI;
    const float thB = acosf(sB / (float)D) * INV2PI;
    const float inv = 1.0f / (float)IN_DIM;

    if (bA < B) {
        if (q0 < D) out[bA * D + q0] = __builtin_amdgcn_cosf((float)q0 * thA) * a0A * inv;
        if (q1 < D) out[bA * D + q1] = __builtin_amdgcn_cosf((float)q1 * thA) * a1A * inv;
    }
    if (bB < B) {
        if (q0 < D) out[bB * D + q0] = __builtin_amdgcn_cosf((float)q0 * thB) * a0B * inv;
        if (q1 < D) out[bB * D + q1] = __builtin_amdgcn_cosf((float)q1 * thB) * a1B * inv;
    }
}

extern "C" void kernel_launch(void* const* d_in, const int* in_sizes, int n_in,
                              void* d_out, int out_size, void* d_ws, size_t ws_size,
                              hipStream_t stream) {
    const float* x    = (const float*)d_in[0];
    const float* W    = (const float*)d_in[1];
    // d_in[2] = theta (unused: corr == 0)
    const int*   dimp = (const int*)d_in[3];
    float*       out  = (float*)d_out;

    const int B = in_sizes[0] / IN_DIM;          // 4096
    const int grid = (B + ROWS - 1) / ROWS;      // 256 blocks x 512 threads = 1/CU

    hipLaunchKernelGGL(kat_kernel, dim3(grid), dim3(BLK), 0, stream,
                       x, W, dimp, out, B);
}